// Round 10
// baseline (289.916 us; speedup 1.0000x reference)
//
#include <hip/hip_runtime.h>

#define STEPS 30
#define HID 32
#define TPB 128                  // 2 waves x 2 chains x 32 = 128 elems per tile
#define EPB 128                  // elements per tile
#define TILES 4                  // tiles per block: persistent, double-buffered
#define LSTRIDE 34               // u16 stride: 68 B -> u32-aligned; 17*row mod 32 hits all banks

typedef float f32x16 __attribute__((ext_vector_type(16)));
typedef __fp16 h8 __attribute__((ext_vector_type(8)));
typedef unsigned int u32x4 __attribute__((ext_vector_type(4)));

// v_cvt_pkrtz_f16_f32 -> packed (lo=x, hi=y) as one 32-bit reg
static __device__ __forceinline__ unsigned int pkrtz_u32(float x, float y) {
    return __builtin_bit_cast(unsigned int, __builtin_amdgcn_cvt_pkrtz(x, y));
}

// Half-wave pair sum via v_permlane32_swap_b32 (VALU) — two "+v" operands force
// distinct physical registers (verified correct in round 9).
static __device__ __forceinline__ float halfsum(float part) {
    float a = part, b = part;
    asm("v_permlane32_swap_b32 %0, %1" : "+v"(a), "+v"(b));
    return a + b;
}

__global__ __launch_bounds__(TPB, 4) void hedge_kernel(
    const float* __restrict__ S,
    const float* __restrict__ W1,
    const float* __restrict__ b1,
    const float* __restrict__ W2,
    const float* __restrict__ b2,
    const float* __restrict__ a_init,
    float* __restrict__ out)
{
    __shared__ unsigned short tile[2][EPB * LSTRIDE];   // 2 x 128 x 34 x 2 = 17408 B
    const int tid  = threadIdx.x;
    const int lane = tid & 63;
    const int wv   = tid >> 6;                 // wave 0..1, owns elems 64*wv..64*wv+63
    const long long blkbase = (long long)blockIdx.x * (TILES * EPB * STEPS);

    // ---- A fragment (constant): W1^aug (32 units x K=16), biases in k0 row. ----
    const int j = lane & 31;
    u32x4 av = {0u, 0u, 0u, 0u};
    if (lane < 32) {
        av[0] = pkrtz_u32(b1[j], W1[0 * HID + j]);           // k0=bias-row(1), k1=s
        av[1] = pkrtz_u32(W1[1 * HID + j], W1[2 * HID + j]); // k2=d, k3=h
    }
    const h8 afrag = __builtin_bit_cast(h8, av);

    // ---- Per-lane W2 slice matching C/D row map: row(r) = (r&3)+8*(r>>2)+4*(lane>>5) ----
    const int rbase = 4 * (lane >> 5);
    float w2r[16];
    #pragma unroll
    for (int r = 0; r < 16; ++r)
        w2r[r] = W2[(r & 3) + 8 * (r >> 2) + rbase];

    const float bias2 = b2[0];
    const float d_init = a_init[0];
    const f32x16 zero16 = {0.f};
    const int erow = 64 * wv + (lane & 31);

    // ---- Prologue: stage tile 0 (f32 -> packed f16 pairs in LDS) ----
    {
        const float2* S2 = (const float2*)(S + blkbase);
        #pragma unroll
        for (int k = 0; k < 15; ++k) {
            int i2 = tid + k * TPB;            // float2 index in [0, 1920)
            float2 v = S2[i2];
            int row = i2 / 15;
            int col = 2 * (i2 - row * 15);     // even -> u32-aligned slot
            *(unsigned*)&tile[0][row * LSTRIDE + col] = pkrtz_u32(v.x, v.y);
        }
    }
    __syncthreads();

    for (int it = 0; it < TILES; ++it) {       // NOT unrolled: keep I-footprint small
        const int cur = it & 1, nxt = cur ^ 1;
        const long long tb = blkbase + (long long)it * (EPB * STEPS);

        // ---- Issue NEXT tile's global loads now; they fly under the compute. ----
        float2 r[15];
        if (it + 1 < TILES) {
            const float2* S2n = (const float2*)(S + tb + EPB * STEPS);
            #pragma unroll
            for (int k = 0; k < 15; ++k)
                r[k] = S2n[tid + k * TPB];
        }

        // ---- Recurrence: R9 core. 2 chains/wave; s from f16 LDS; dn stored f16. ----
        unsigned short* myA = &tile[cur][erow * LSTRIDE];
        unsigned short* myB = myA + 32 * LSTRIDE;
        float dA = d_init, hA = 0.0f;
        float dB = d_init, hB = 0.0f;
        #pragma unroll
        for (int t = 0; t < STEPS; ++t) {
            const unsigned sA16 = myA[t];      // ds_read_u16, conflict-free
            const unsigned sB16 = myB[t];

            u32x4 bvA, bvB;
            bvA[0] = 0x3C00u | (sA16 << 16);   // == pkrtz(1.0f, s): k0=1, k1=s
            bvA[1] = pkrtz_u32(dA, hA);        // k2=d, k3=h
            bvA[2] = 0u; bvA[3] = 0u;
            bvB[0] = 0x3C00u | (sB16 << 16);
            bvB[1] = pkrtz_u32(dB, hB);
            bvB[2] = 0u; bvB[3] = 0u;

            const f32x16 PA = __builtin_amdgcn_mfma_f32_32x32x16_f16(
                afrag, __builtin_bit_cast(h8, bvA), zero16, 0, 0, 0);
            const f32x16 PB = __builtin_amdgcn_mfma_f32_32x32x16_f16(
                afrag, __builtin_bit_cast(h8, bvB), zero16, 0, 0, 0);

            float a0 = 0.f, a1 = 0.f, a2 = 0.f, a3 = 0.f;
            float b0 = 0.f, b1v = 0.f, b2v = 0.f, b3 = 0.f;
            #pragma unroll
            for (int q = 0; q < 16; q += 4) {
                a0  = fmaf(w2r[q + 0], fmaxf(PA[q + 0], 0.f), a0);
                a1  = fmaf(w2r[q + 1], fmaxf(PA[q + 1], 0.f), a1);
                a2  = fmaf(w2r[q + 2], fmaxf(PA[q + 2], 0.f), a2);
                a3  = fmaf(w2r[q + 3], fmaxf(PA[q + 3], 0.f), a3);
                b0  = fmaf(w2r[q + 0], fmaxf(PB[q + 0], 0.f), b0);
                b1v = fmaf(w2r[q + 1], fmaxf(PB[q + 1], 0.f), b1v);
                b2v = fmaf(w2r[q + 2], fmaxf(PB[q + 2], 0.f), b2v);
                b3  = fmaf(w2r[q + 3], fmaxf(PB[q + 3], 0.f), b3);
            }
            const float partA = (a0 + a1) + (a2 + a3);
            const float partB = (b0 + b1v) + (b2v + b3);
            const float dnA = bias2 + halfsum(partA);
            const float dnB = bias2 + halfsum(partB);
            hA = fmaf(0.2f, dnA, 0.8f * hA);
            hB = fmaf(0.2f, dnB, 0.8f * hB);
            dA = dnA;
            dB = dnB;
            if (lane < 32) {                   // store dn as f16 (RNE); d-chain stays f32
                myA[t] = __builtin_bit_cast(unsigned short, (_Float16)dnA);
                myB[t] = __builtin_bit_cast(unsigned short, (_Float16)dnB);
            }
        }
        __syncthreads();                       // compute writes -> dump reads (cross-thread)

        // ---- Dump tile (f16 -> f32, coalesced float2 stores; fire-and-forget) ----
        {
            float2* O2 = (float2*)(out + tb);
            #pragma unroll
            for (int k = 0; k < 15; ++k) {
                int i2 = tid + k * TPB;
                int row = i2 / 15;
                int col = 2 * (i2 - row * 15);
                unsigned u = *(const unsigned*)&tile[cur][row * LSTRIDE + col];
                float lo = (float)__builtin_bit_cast(_Float16, (unsigned short)(u & 0xffffu));
                float hi = (float)__builtin_bit_cast(_Float16, (unsigned short)(u >> 16));
                O2[i2] = make_float2(lo, hi);
            }
        }

        // ---- Stage next tile from the in-flight registers into the other buffer ----
        if (it + 1 < TILES) {
            #pragma unroll
            for (int k = 0; k < 15; ++k) {
                int i2 = tid + k * TPB;
                int row = i2 / 15;
                int col = 2 * (i2 - row * 15);
                *(unsigned*)&tile[nxt][row * LSTRIDE + col] = pkrtz_u32(r[k].x, r[k].y);
            }
        }
        __syncthreads();                       // stage writes -> next iter's compute reads
    }
}

extern "C" void kernel_launch(void* const* d_in, const int* in_sizes, int n_in,
                              void* d_out, int out_size, void* d_ws, size_t ws_size,
                              hipStream_t stream) {
    const float* S      = (const float*)d_in[0];
    const float* W1     = (const float*)d_in[1];
    const float* b1     = (const float*)d_in[2];
    const float* W2     = (const float*)d_in[3];
    const float* b2     = (const float*)d_in[4];
    const float* a_init = (const float*)d_in[5];
    float* out = (float*)d_out;

    const int batch = in_sizes[0] / STEPS;        // 1048576
    const int grid  = batch / (EPB * TILES);      // 2048 persistent blocks (8/CU)
    hedge_kernel<<<grid, TPB, 0, stream>>>(S, W1, b1, W2, b2, a_init, out);
}